// Round 7
// baseline (207.873 us; speedup 1.0000x reference)
//
#include <hip/hip_runtime.h>
#include <math.h>

// FFTChainMatrix, fused frequency-domain factorization with an intra-block
// 2-tile software pipeline.
//   prep : build Bf (33 x 128 x 128 spectral operator), Dt2, E2 tables.
//   fused: 256 blocks x 512 thr (8 waves), 16 tokens = 2 tiles x 8 tokens,
//          LDS split in two 68KB halves (one per tile):
//     A_k: DFT of tile k        (HBM reads, MFMA K=64, scatter to sm[k])
//     B_k: per-f YF=XF.Bf^T     (L2 reads, M=8 MFMA, in place in sm[k])
//     C_k: iDFT + y stores      (LDS gather, MFMA, HBM writes)
//   schedule: A0 | B0 + A1-loads-in-flight | C0 + B1 (stores drain under L2)
//             | C1.  v1-v4 showed lockstep phases leave every pipe <25% busy;
//   this overlaps HBM-read, L2-read and HBM-write classes across tiles.
//   v6: sched_barrier(0) -> asm memory fence (suspected compile-time
//   pathology in the huge unrolled body caused 2x container failure).

typedef unsigned short u16;
typedef unsigned int   u32;
typedef __attribute__((ext_vector_type(8))) short bf16x8;
typedef __attribute__((ext_vector_type(4))) float f32x4;

#define TWO_PI 6.2831853071795864769f

#define SF 1032                          // u16 per f-slice (8*128 + 8 pad)
#define TILE_ELEMS (33u * SF)            // 34056 u16 = 68112 B per tile
#define BF_ELEMS (33u*128u*128u)         // 540672 u16
#define DT_OFF   BF_ELEMS
#define DT_ELEMS (2u*4u*80u*8u)          // 5120  : [kt][q][n(80)][8]
#define E_OFF    (DT_OFF + DT_ELEMS)
#define E_ELEMS  (3u*4u*64u*8u)          // 6144  : [kt][q][t(64)][8]

__device__ __forceinline__ u16 f2bf(float f) {   // RNE fp32 -> bf16
    union { float f; unsigned u; } v; v.f = f;
    unsigned r = v.u + 0x7FFFu + ((v.u >> 16) & 1u);
    return (u16)(r >> 16);
}

// ---- prep: block 0 -> Dt2/E2 tables; blocks 1..1024 -> Bf ------------------
__global__ void prep(const float* __restrict__ p, const float* __restrict__ cw,
                     u16* __restrict__ Bf, u16* __restrict__ Dt, u16* __restrict__ E) {
    const int tid = threadIdx.x;
    if (blockIdx.x == 0) {
        for (int e = tid; e < (int)DT_ELEMS; e += 256) {
            int j = e & 7, rowid = e >> 3;
            int n = rowid % 80, grp = rowid / 80;          // grp = kt*4+q
            int k = (grp >> 2) * 32 + (grp & 3) * 8 + j;
            float v = 0.f;
            if (n < 66) {
                int f = n >> 1;
                float ang = TWO_PI * (float)((f * k) & 63) * (1.f / 64.f);
                v = (n & 1) ? -sinf(ang) : cosf(ang);
            }
            Dt[e] = f2bf(v);
        }
        for (int e = tid; e < (int)E_ELEMS; e += 256) {
            int j = e & 7, rowid = e >> 3;
            int t = rowid % 64, grp = rowid / 64;          // grp = kt*4+q
            int k = (grp >> 2) * 32 + (grp & 3) * 8 + j;
            float v = 0.f;
            if (k < 66) {
                int f = k >> 1;
                float wf = (f == 0 || f == 32) ? 1.f : 2.f;
                float ang = TWO_PI * (float)((f * t) & 63) * (1.f / 64.f);
                v = (wf * (1.f / 64.f)) * ((k & 1) ? -sinf(ang) : cosf(ang));
            }
            E[e] = f2bf(v);
        }
        return;
    }
    __shared__ float  ct[4][64];
    __shared__ float2 trig[64];
    const int pr = tid >> 6, ln = tid & 63;
    if (tid < 64) {
        float s, c;
        sincosf(TWO_PI * (float)tid * (1.f / 64.f), &s, &c);
        trig[tid] = make_float2(s, c);
    }
    const int pg = (blockIdx.x - 1) * 4 + pr;     // 0..4095
    const int o = pg >> 6, i = pg & 63;
    {
        const float* base = p + (size_t)o * 4096 + i * 64 + ln;
        ct[pr][ln] = cw[0] * base[0]      + cw[1] * base[262144]
                   + cw[2] * base[524288] + cw[3] * base[786432];
    }
    __syncthreads();
    if (ln < 33) {        // f = ln
        float cr = 0.f, ci = 0.f;
        for (int u = 0; u < 64; ++u) {
            float2 sc = trig[(ln * u) & 63];
            cr += ct[pr][u] * sc.y; ci -= ct[pr][u] * sc.x;
        }
        u16* b = Bf + (size_t)ln * 16384 + (2 * o) * 128 + 2 * i;
        b[0]   = f2bf(cr);  b[1]   = f2bf(-ci);
        b[128] = f2bf(ci);  b[129] = f2bf(cr);
    }
}

// ---- fused: 2-tile pipelined DFT -> per-f GEMM -> iDFT ---------------------
__global__ __launch_bounds__(512, 2) void fused(const float* __restrict__ x,
                                                const u16* __restrict__ Dt,
                                                const u16* __restrict__ Bf,
                                                const u16* __restrict__ E2,
                                                float* __restrict__ y) {
    __shared__ u16 sm[2 * TILE_ELEMS];   // 136,224 B -> 1 block/CU
    const int tid = threadIdx.x, lane = tid & 63, wave = tid >> 6;
    const int lm = lane & 15, q = lane >> 4, kq8 = q * 8, r0 = q * 4;
    const float* xb = x + (size_t)blockIdx.x * 65536u;   // 16 tok * 4096

#define LOADX(XV, tile)                                                      \
    _Pragma("unroll") for (int kt = 0; kt < 2; ++kt)                         \
    _Pragma("unroll") for (int mi = 0; mi < 4; ++mi) {                       \
        const float* rp = xb + (tile)*32768 + (wave*64 + mi*16 + lm)*64      \
                             + kt*32 + kq8;                                  \
        XV[kt][mi][0] = *(const float4*)rp;                                  \
        XV[kt][mi][1] = *(const float4*)(rp + 4);                            \
    }
#define A_MFMA(XV, ACC)                                                      \
    _Pragma("unroll") for (int kt = 0; kt < 2; ++kt)                         \
    _Pragma("unroll") for (int mi = 0; mi < 4; ++mi) {                       \
        union { u16 u[8]; bf16x8 v; } pk;                                    \
        float4 p0 = XV[kt][mi][0], p1 = XV[kt][mi][1];                       \
        pk.u[0]=f2bf(p0.x); pk.u[1]=f2bf(p0.y);                              \
        pk.u[2]=f2bf(p0.z); pk.u[3]=f2bf(p0.w);                              \
        pk.u[4]=f2bf(p1.x); pk.u[5]=f2bf(p1.y);                              \
        pk.u[6]=f2bf(p1.z); pk.u[7]=f2bf(p1.w);                              \
        _Pragma("unroll") for (int ni = 0; ni < 5; ++ni)                     \
            ACC[mi][ni] = __builtin_amdgcn_mfma_f32_16x16x32_bf16(           \
                pk.v, bfr[kt][ni], ACC[mi][ni], 0, 0, 0);                    \
    }
#define SCATTER(ACC, base)                                                   \
    {   const int sw = wave << 3;  /* tok == wave, < 8 */                    \
        _Pragma("unroll") for (int mi = 0; mi < 4; ++mi)                     \
        _Pragma("unroll") for (int ni = 0; ni < 5; ++ni) {                   \
            const int col = ni*16 + lm;                                      \
            if (col < 66) {                                                  \
                const int f = col >> 1, par = col & 1;                       \
                f32x4 v = ACC[mi][ni];                                       \
                _Pragma("unroll") for (int r = 0; r < 4; ++r) {              \
                    int ii = mi*16 + r0 + r;                                 \
                    sm[(base) + f*SF + wave*128 + (((ii<<1)|par) ^ sw)]      \
                        = f2bf(v[r]);                                        \
                }                                                            \
            }                                                                \
        }                                                                    \
    }
// phase B main (f<32), M=8 (rows dup), Bf frags double-buffered from L2
#define PHASE_B(base)                                                        \
    _Pragma("unroll") for (int t = 0; t < 4; ++t) {                          \
        const int f = t*8 + wave;                                            \
        u16* sl = &sm[(base) + f * SF];                                      \
        const u16* Bff = Bf + (size_t)f * 16384;                             \
        bf16x8 af[4];                                                        \
        _Pragma("unroll") for (int ks = 0; ks < 4; ++ks)                     \
            af[ks] = *(const bf16x8*)&sl[(lm&7)*128                          \
                                         + ((ks*32 + kq8) ^ ((lm&7)<<3))];  \
        bf16x8 bc[4], bn[4];                                                 \
        _Pragma("unroll") for (int ks = 0; ks < 4; ++ks)                     \
            bc[ks] = *(const bf16x8*)&Bff[lm*128 + ks*32 + kq8];             \
        _Pragma("unroll") for (int nt = 0; nt < 8; ++nt) {                   \
            if (nt < 7)                                                      \
                _Pragma("unroll") for (int ks = 0; ks < 4; ++ks)             \
                    bn[ks] = *(const bf16x8*)&Bff[((nt+1)*16 + lm)*128       \
                                                  + ks*32 + kq8];            \
            f32x4 c = (f32x4){0.f,0.f,0.f,0.f};                              \
            _Pragma("unroll") for (int ks = 0; ks < 4; ++ks)                 \
                c = __builtin_amdgcn_mfma_f32_16x16x32_bf16(                 \
                    af[ks], bc[ks], c, 0, 0, 0);                             \
            if (q < 2)                                                       \
                _Pragma("unroll") for (int r = 0; r < 4; ++r) {              \
                    int tok = r0 + r;                                        \
                    sl[tok*128 + ((nt*16 + lm) ^ (tok<<3))] = f2bf(c[r]);    \
                }                                                            \
            _Pragma("unroll") for (int ks = 0; ks < 4; ++ks) bc[ks] = bn[ks];\
        }                                                                    \
    }
// f=32 slice: compute + write (A-frags pre-read before a barrier), nt = wave
#define PHASE_B32(base, AF)                                                  \
    {   f32x4 c = (f32x4){0.f,0.f,0.f,0.f};                                  \
        _Pragma("unroll") for (int ks = 0; ks < 4; ++ks)                     \
            c = __builtin_amdgcn_mfma_f32_16x16x32_bf16(                     \
                AF[ks], bq32[ks], c, 0, 0, 0);                               \
        if (q < 2)                                                           \
            _Pragma("unroll") for (int r = 0; r < 4; ++r) {                  \
                int tok = r0 + r;                                            \
                sm[(base) + 32*SF + tok*128 + ((wave*16 + lm) ^ (tok<<3))]   \
                    = f2bf(c[r]);                                            \
            }                                                                \
    }
#define PHASE_C(base, tile)                                                  \
    _Pragma("unroll") for (int nt = 0; nt < 4; ++nt) {                       \
        const int o = nt*16 + lm;                                            \
        const int cb = wave*128 + ((2*o) ^ (wave<<3));                       \
        f32x4 acc[4];                                                        \
        _Pragma("unroll") for (int mt = 0; mt < 4; ++mt)                     \
            acc[mt] = (f32x4){0.f,0.f,0.f,0.f};                              \
        _Pragma("unroll") for (int kt = 0; kt < 3; ++kt) {                   \
            union { u32 w[4]; bf16x8 v; } bq;                                \
            _Pragma("unroll") for (int j = 0; j < 4; ++j) {                  \
                int f = kt*16 + q*4 + j;                                     \
                u32 vv = 0u;                                                 \
                if (f < 33) vv = *(const u32*)&sm[(base) + f*SF + cb];       \
                bq.w[j] = vv;                                                \
            }                                                                \
            _Pragma("unroll") for (int mt = 0; mt < 4; ++mt)                 \
                acc[mt] = __builtin_amdgcn_mfma_f32_16x16x32_bf16(           \
                    ef[kt][mt], bq.v, acc[mt], 0, 0, 0);                     \
        }                                                                    \
        float* yb = y + ((size_t)(blockIdx.x*16 + (tile)*8 + wave))*4096     \
                      + o*64;                                                \
        _Pragma("unroll") for (int mt = 0; mt < 4; ++mt) {                   \
            float4 st = { acc[mt][0], acc[mt][1], acc[mt][2], acc[mt][3] };  \
            *(float4*)&yb[mt*16 + r0] = st;                                  \
        }                                                                    \
    }

    // hoists: DFT basis frags, iDFT basis frags, f=32 B-operand (all L2-hot)
    bf16x8 bfr[2][5];
#pragma unroll
    for (int kt = 0; kt < 2; ++kt)
#pragma unroll
        for (int ni = 0; ni < 5; ++ni)
            bfr[kt][ni] = *(const bf16x8*)&Dt[((kt*4 + q)*80 + ni*16 + lm)*8];
    bf16x8 ef[3][4];
#pragma unroll
    for (int kt = 0; kt < 3; ++kt)
#pragma unroll
        for (int mt = 0; mt < 4; ++mt)
            ef[kt][mt] = *(const bf16x8*)&E2[((kt*4 + q)*64 + mt*16 + lm)*8];
    bf16x8 bq32[4];
#pragma unroll
    for (int ks = 0; ks < 4; ++ks)
        bq32[ks] = *(const bf16x8*)&Bf[(size_t)32*16384
                                       + (wave*16 + lm)*128 + ks*32 + kq8];

    // ---- A0: DFT tile 0 ----------------------------------------------------
    {
        float4 xv[2][4][2];
        LOADX(xv, 0)
        f32x4 acc[4][5];
#pragma unroll
        for (int mi = 0; mi < 4; ++mi)
#pragma unroll
            for (int ni = 0; ni < 5; ++ni) acc[mi][ni] = (f32x4){0.f,0.f,0.f,0.f};
        A_MFMA(xv, acc)
        SCATTER(acc, 0)
    }
    __syncthreads();                       // bar1: XF0 complete
    bf16x8 af32a[4];
#pragma unroll
    for (int ks = 0; ks < 4; ++ks)         // f=32 A-frags (all waves read)
        af32a[ks] = *(const bf16x8*)&sm[32*SF + (lm&7)*128
                                        + ((ks*32 + kq8) ^ ((lm&7)<<3))];
    __syncthreads();                       // bar2: f32 reads precede B0 writes

    // ---- B0 with A1's x-loads in flight ------------------------------------
    float4 xv1[2][4][2];
    LOADX(xv1, 1)                          // 16 HBM loads issued...
    asm volatile("" ::: "memory");         // ...pinned before B0 (compiler fence)
    PHASE_B(0)
    PHASE_B32(0, af32a)
    {   // A1 compute + scatter into sm[1] (disjoint from B0's sm[0])
        f32x4 acc[4][5];
#pragma unroll
        for (int mi = 0; mi < 4; ++mi)
#pragma unroll
            for (int ni = 0; ni < 5; ++ni) acc[mi][ni] = (f32x4){0.f,0.f,0.f,0.f};
        A_MFMA(xv1, acc)
        SCATTER(acc, TILE_ELEMS)
    }
    __syncthreads();                       // bar3: YF0 + XF1 complete
    bf16x8 af32b[4];
#pragma unroll
    for (int ks = 0; ks < 4; ++ks)
        af32b[ks] = *(const bf16x8*)&sm[TILE_ELEMS + 32*SF + (lm&7)*128
                                        + ((ks*32 + kq8) ^ ((lm&7)<<3))];
    __syncthreads();                       // bar4: f32 reads precede B1 writes

    // ---- C0 (stores drain async) then B1 (L2 under the store shadow) -------
    PHASE_C(0, 0)
    PHASE_B(TILE_ELEMS)
    PHASE_B32(TILE_ELEMS, af32b)
    __syncthreads();                       // bar5: YF1 complete
    PHASE_C(TILE_ELEMS, 1)
}

extern "C" void kernel_launch(void* const* d_in, const int* in_sizes, int n_in,
                              void* d_out, int out_size, void* d_ws, size_t ws_size,
                              hipStream_t stream) {
    const float* x      = (const float*)d_in[0];  // (2,2048,4096) fp32
    const float* params = (const float*)d_in[1];  // (4,64,64,64)  fp32
    const float* cw     = (const float*)d_in[2];  // (4,)          fp32
    float* out = (float*)d_out;

    u16* Bf = (u16*)d_ws;
    u16* Dt = Bf + DT_OFF;
    u16* Eg = Bf + E_OFF;

    prep<<<1025, 256, 0, stream>>>(params, cw, Bf, Dt, Eg);
    fused<<<256, 512, 0, stream>>>(x, Dt, Bf, Eg, out);
}